// Round 5
// baseline (129.605 us; speedup 1.0000x reference)
//
#include <hip/hip_runtime.h>
#include <math.h>

// n=16384 Gaussian points in 3D. Exact 12-NN (incl self) per point:
//   out[i] = b + ( (W·p_i)·(1 + 11/sqrt(2)) + 0.5 * sum_{11NN} W·|p_i - p_j| ) / 12
//
// R19: sort side closed (R18: one self-sufficient plain dispatch, <15 µs).
// Query was VALU-issue+latency bound: 67 µs, VALUBusy 48%, occ 36% —
// ~2400 VALU insts/wave with 52% stall (shfl dep-chains + L2 latency).
// This round: TWO queries per wave (adjacent ranks 2g, 2g+1). Every
// dependent chain gets an independent twin -> dual-issue covers stalls.
// Joint extent loop for min(stepsA,stepsB), single-query tails. Waves
// 16384 -> 8192. Same math per query (exact); sort_kernel unchanged.
//
// Per query: best-axis slab; seed 768 around bin-estimated rank -> u =
// 12th of 64 lane minima (valid UB of tau) -> extent from prefix sums ->
// collect into 4-deep paired (d2,w) queue -> 12-round paired knockout
// (exact take-12, first-lane tie-break) -> reduce. Rare overflow
// (wave-uniform) -> exact med3 fallback over the same extent. Self w=0.

#define NBINS  2048
#define PARTS  16
#define CMIN_  (-6.0f)
#define INVBW_ ((float)NBINS / 12.0f)
#define BLOCK  256
#define SEED   768
#define KK     12
#define CD     4
#define BIG    3.0e38f

__device__ __forceinline__ int bin_of(float x) {
  int b = (int)((x - CMIN_) * INVBW_);
  b = b < 0 ? 0 : b;
  b = b > NBINS - 1 ? NBINS - 1 : b;
  return b;
}

__device__ __forceinline__ float wave_min(float v) {
#pragma unroll
  for (int o = 1; o < 64; o <<= 1) v = fminf(v, __shfl_xor(v, o));
  return v;
}

// sorted ascending 4-deep paired insert (static indexing -> registers)
__device__ __forceinline__ void ins4(float (&qd)[CD], float (&qw)[CD],
                                     float d, float w) {
#pragma unroll
  for (int k = CD - 1; k >= 1; --k) {
    const bool up  = (qd[k - 1] > d);
    const bool mid = (qd[k] > d);
    const float nd = up ? qd[k - 1] : (mid ? d : qd[k]);
    const float nw = up ? qw[k - 1] : (mid ? w : qw[k]);
    qd[k] = nd; qw[k] = nw;
  }
  if (qd[0] > d) { qw[0] = w; qd[0] = d; }
}

// ---------------- K1: self-sufficient fused sort (grid = 3*PARTS, plain) ----
__global__ __launch_bounds__(1024)
void sort_kernel(const float* __restrict__ p, int* __restrict__ c_all,
                 float4* __restrict__ s_all, int n) {
  __shared__ int h_all[NBINS];   // full per-axis histogram
  __shared__ int h_pre[NBINS];   // hist of indices < myStart; later: cursors
  __shared__ int wsum[16];
  const int tid  = threadIdx.x;
  const int dim  = blockIdx.x / PARTS;
  const int part = blockIdx.x % PARTS;
  const int chunk   = (n + PARTS - 1) / PARTS;
  const int myStart = part * chunk;
  const int myEnd   = min(myStart + chunk, n);

  h_all[tid] = 0; h_all[tid + 1024] = 0;
  h_pre[tid] = 0; h_pre[tid + 1024] = 0;
  __syncthreads();

  for (int i = tid; i < n; i += 1024) {
    const int b = bin_of(p[3 * i + dim]);
    atomicAdd(&h_all[b], 1);
    if (i < myStart) atomicAdd(&h_pre[b], 1);   // wave-uniform predicate
  }
  __syncthreads();

  const int a = h_all[2 * tid], b = h_all[2 * tid + 1];
  const int v = a + b;
  const int lane = tid & 63, wid = tid >> 6;     // 16 waves
  int incl = v;
#pragma unroll
  for (int o = 1; o < 64; o <<= 1) {
    const int t = __shfl_up(incl, o);
    if (lane >= o) incl += t;
  }
  if (lane == 63) wsum[wid] = incl;
  __syncthreads();
  int woff = 0;
  for (int wI = 0; wI < wid; ++wI) woff += wsum[wI];   // broadcast reads
  const int excl = woff + incl - v;                    // start of bin 2*tid

  if (part == 0) {
    int* __restrict__ cursor = c_all + (size_t)dim * NBINS;
    cursor[2 * tid]     = excl + a;
    cursor[2 * tid + 1] = excl + a + b;
  }

  const int c0 = excl + h_pre[2 * tid];
  const int c1 = excl + a + h_pre[2 * tid + 1];
  __syncthreads();
  h_pre[2 * tid]     = c0;
  h_pre[2 * tid + 1] = c1;
  __syncthreads();

  float4* __restrict__ sorted = s_all + (size_t)dim * n;
  for (int i = myStart + tid; i < myEnd; i += 1024) {
    const float x = p[3 * i], y = p[3 * i + 1], z = p[3 * i + 2];
    const float c = (dim == 0) ? x : (dim == 1) ? y : z;
    const int pos = atomicAdd(&h_pre[bin_of(c)], 1);
    sorted[pos] = make_float4(x, y, z, __int_as_float(i));
  }
}

// ---------------- K2 helpers -------------------------------------------------
struct Q {
  float xi, yi, zi, cq;
  int orig;
  const float4* sv;
  const int* cur;
};

__device__ __forceinline__ Q make_q(const float4* sx, const float4* sy,
                                    const float4* sz, const int* cx,
                                    const int* cy, const int* cz, int t) {
  Q q;
  const float4 me = sx[t];
  q.xi = me.x; q.yi = me.y; q.zi = me.z; q.orig = __float_as_int(me.w);
  const float ax = fabsf(q.xi), ay = fabsf(q.yi), az = fabsf(q.zi);
  if (ay >= ax && ay >= az)      { q.sv = sy; q.cur = cy; q.cq = q.yi; }
  else if (az >= ax && az >= ay) { q.sv = sz; q.cur = cz; q.cq = q.zi; }
  else                           { q.sv = sx; q.cur = cx; q.cq = q.xi; }
  return q;
}

__device__ __forceinline__ int seed_lo(const Q& q, int n) {
  const int bq = bin_of(q.cq);
  const int bs = (bq > 0) ? q.cur[bq - 1] : 0;
  const int be = q.cur[bq];
  int lo = ((bs + be) >> 1) - SEED / 2;
  lo = lo < 0 ? 0 : lo;
  lo = lo > n - SEED ? n - SEED : lo;
  return lo;
}

// single-query exact extraction (12 rounds, first-lane tie-break)
__device__ __forceinline__ float extract12(float (&qd)[CD], float (&qw)[CD],
                                           int lane) {
  float acc = 0.f;
#pragma unroll
  for (int r = 0; r < KK; ++r) {
    const float mm = wave_min(qd[0]);
    const unsigned long long bal = __ballot(qd[0] == mm);
    if (qd[0] == mm && lane == (int)(__ffsll(bal) - 1)) {
      acc += qw[0];
#pragma unroll
      for (int k = 0; k < CD - 1; ++k) { qd[k] = qd[k + 1]; qw[k] = qw[k + 1]; }
      qd[CD - 1] = BIG;
    }
  }
  return acc;
}

// rare exact fallback over the extent: med3 top-12 -> tau -> rescan
__device__ __forceinline__ float fallback12(const Q& q, int lo2, int hi2,
                                            int steps, float W0, float W1,
                                            float W2, int lane) {
  float dd[KK];
#pragma unroll
  for (int k = 0; k < KK; ++k) dd[k] = BIG;
  for (int s0 = 0; s0 < steps; ++s0) {
    const int pos = lo2 + s0 * 64 + lane;
    const float4 c = q.sv[(pos < hi2) ? pos : hi2 - 1];
    const float dx = q.xi - c.x, dy = q.yi - c.y, dz = q.zi - c.z;
    const float d2 = (pos < hi2) ? fmaf(dx, dx, fmaf(dy, dy, dz * dz)) : BIG;
#pragma unroll
    for (int k = KK - 1; k >= 1; --k)
      dd[k] = __builtin_amdgcn_fmed3f(d2, dd[k - 1], dd[k]);
    dd[0] = fminf(dd[0], d2);
  }
  float tau = 0.f;
#pragma unroll
  for (int r = 0; r < KK; ++r) {
    const float mm = wave_min(dd[0]);
    if (dd[0] == mm) {
#pragma unroll
      for (int k = 0; k < KK - 1; ++k) dd[k] = dd[k + 1];
      dd[KK - 1] = BIG;
    }
    tau = mm;
  }
  float acc = 0.f;
  for (int s0 = 0; s0 < steps; ++s0) {
    const int pos = lo2 + s0 * 64 + lane;
    if (pos < hi2) {
      const float4 c = q.sv[pos];
      const float dx = q.xi - c.x, dy = q.yi - c.y, dz = q.zi - c.z;
      const float d2 = fmaf(dx, dx, fmaf(dy, dy, dz * dz));
      const float w  = fmaf(W0, fabsf(dx), fmaf(W1, fabsf(dy), W2 * fabsf(dz)));
      acc += (d2 <= tau) ? w : 0.f;
    }
  }
  return acc;
}

// one collect step for one query (clamped load, lane guard in condition)
__device__ __forceinline__ void step1(const Q& q, float u, int pos, int hi2,
                                      float W0, float W1, float W2,
                                      float (&qd)[CD], float (&qw)[CD],
                                      int& ccnt) {
  const float4 c = q.sv[(pos < hi2) ? pos : hi2 - 1];
  const float dx = q.xi - c.x, dy = q.yi - c.y, dz = q.zi - c.z;
  const float d2 = fmaf(dx, dx, fmaf(dy, dy, dz * dz));
  if (d2 <= u && pos < hi2) {
    const float w = fmaf(W0, fabsf(dx), fmaf(W1, fabsf(dy), W2 * fabsf(dz)));
    ++ccnt; ins4(qd, qw, d2, w);
  }
}

// ---------------- K2: dual-query wave kernel --------------------------------
__global__ __launch_bounds__(BLOCK)
void query_kernel(const float4* __restrict__ sx, const float4* __restrict__ sy,
                  const float4* __restrict__ sz, const int* __restrict__ cx,
                  const int* __restrict__ cy, const int* __restrict__ cz,
                  const float* __restrict__ W, const float* __restrict__ bias,
                  float* __restrict__ out, int n) {
  const int lane = threadIdx.x & 63;
  const int wv   = threadIdx.x >> 6;
  const int gw   = blockIdx.x * (BLOCK / 64) + wv;   // global wave id
  const float W0 = W[0], W1 = W[1], W2 = W[2];
  const float bb = bias[0];

  Q a = make_q(sx, sy, sz, cx, cy, cz, 2 * gw);
  Q b = make_q(sx, sy, sz, cx, cy, cz, 2 * gw + 1);

  const float4* baseA = a.sv + seed_lo(a, n) + lane;
  const float4* baseB = b.sv + seed_lo(b, n) + lane;

  // ---- 1. seed lane-minima (dual, independent chains) ----
  float mA = BIG, mB = BIG;
#pragma unroll
  for (int s = 0; s < SEED / 64; ++s) {
    const float4 cA = baseA[s * 64];
    const float4 cB = baseB[s * 64];
    {
      const float dx = a.xi - cA.x, dy = a.yi - cA.y, dz = a.zi - cA.z;
      mA = fminf(mA, fmaf(dx, dx, fmaf(dy, dy, dz * dz)));
    }
    {
      const float dx = b.xi - cB.x, dy = b.yi - cB.y, dz = b.zi - cB.z;
      mB = fminf(mB, fmaf(dx, dx, fmaf(dy, dy, dz * dz)));
    }
  }

  // ---- 2. u = 12th smallest of 64 lane minima (dual knockout) ----
  float uA, uB;
  {
    float vA = mA, vB = mB;
#pragma unroll
    for (int r = 0; r < KK; ++r) {
      float wA = vA, wB = vB;
#pragma unroll
      for (int o = 1; o < 64; o <<= 1) {
        wA = fminf(wA, __shfl_xor(wA, o));
        wB = fminf(wB, __shfl_xor(wB, o));
      }
      uA = wA; uB = wB;
      vA = (vA == wA) ? BIG : vA;
      vB = (vB == wB) ? BIG : vB;
    }
  }

  // ---- 3. extents from prefix sums ----
  int lo2A, hi2A, lo2B, hi2B;
  {
    const float sA = sqrtf(uA);
    const int blA = bin_of(a.cq - sA), bhA = bin_of(a.cq + sA);
    lo2A = (blA > 0) ? a.cur[blA - 1] : 0;
    hi2A = a.cur[bhA];
    const float sB = sqrtf(uB);
    const int blB = bin_of(b.cq - sB), bhB = bin_of(b.cq + sB);
    lo2B = (blB > 0) ? b.cur[blB - 1] : 0;
    hi2B = b.cur[bhB];
  }
  const int stepsA = (hi2A - lo2A + 63) >> 6;
  const int stepsB = (hi2B - lo2B + 63) >> 6;
  const int stepsMin = min(stepsA, stepsB);

  // ---- collect-scan: joint loop + single tails ----
  float qdA[CD], qwA[CD], qdB[CD], qwB[CD];
  int ccA = 0, ccB = 0;
#pragma unroll
  for (int k = 0; k < CD; ++k) {
    qdA[k] = BIG; qwA[k] = 0.f; qdB[k] = BIG; qwB[k] = 0.f;
  }

  int st = 0;
  for (; st < stepsMin; ++st) {
    const int posA = lo2A + st * 64 + lane;
    const int posB = lo2B + st * 64 + lane;
    step1(a, uA, posA, hi2A, W0, W1, W2, qdA, qwA, ccA);
    step1(b, uB, posB, hi2B, W0, W1, W2, qdB, qwB, ccB);
  }
  for (; st < stepsA; ++st)
    step1(a, uA, lo2A + st * 64 + lane, hi2A, W0, W1, W2, qdA, qwA, ccA);
  for (; st < stepsB; ++st)
    step1(b, uB, lo2B + st * 64 + lane, hi2B, W0, W1, W2, qdB, qwB, ccB);

  // ---- 4. exact take-12 (dual interleaved fast path) ----
  float accA = 0.f, accB = 0.f;
  const bool ovfA = __ballot(ccA > CD) != 0ULL;   // wave-uniform
  const bool ovfB = __ballot(ccB > CD) != 0ULL;
  if (!ovfA && !ovfB) {
#pragma unroll
    for (int r = 0; r < KK; ++r) {
      float ma = qdA[0], mb = qdB[0];
#pragma unroll
      for (int o = 1; o < 64; o <<= 1) {
        ma = fminf(ma, __shfl_xor(ma, o));
        mb = fminf(mb, __shfl_xor(mb, o));
      }
      const unsigned long long balA = __ballot(qdA[0] == ma);
      const unsigned long long balB = __ballot(qdB[0] == mb);
      if (qdA[0] == ma && lane == (int)(__ffsll(balA) - 1)) {
        accA += qwA[0];
#pragma unroll
        for (int k = 0; k < CD - 1; ++k) { qdA[k] = qdA[k + 1]; qwA[k] = qwA[k + 1]; }
        qdA[CD - 1] = BIG;
      }
      if (qdB[0] == mb && lane == (int)(__ffsll(balB) - 1)) {
        accB += qwB[0];
#pragma unroll
        for (int k = 0; k < CD - 1; ++k) { qdB[k] = qdB[k + 1]; qwB[k] = qwB[k + 1]; }
        qdB[CD - 1] = BIG;
      }
    }
  } else {
    accA = ovfA ? fallback12(a, lo2A, hi2A, stepsA, W0, W1, W2, lane)
                : extract12(qdA, qwA, lane);
    accB = ovfB ? fallback12(b, lo2B, hi2B, stepsB, W0, W1, W2, lane)
                : extract12(qdB, qwB, lane);
  }

  // ---- 5. reduce + write (dual) ----
#pragma unroll
  for (int o = 1; o < 64; o <<= 1) {
    accA += __shfl_xor(accA, o);
    accB += __shfl_xor(accB, o);
  }
  if (lane == 0) {
    const float xwA = W0 * a.xi + W1 * a.yi + W2 * a.zi;
    const float xwB = W0 * b.xi + W1 * b.yi + W2 * b.zi;
    // 1 + 11/sqrt(2)
    out[a.orig] = bb + (xwA * 8.778174593052022f + 0.5f * accA) * (1.0f / 12.0f);
    out[b.orig] = bb + (xwB * 8.778174593052022f + 0.5f * accB) * (1.0f / 12.0f);
  }
}

extern "C" void kernel_launch(void* const* d_in, const int* in_sizes, int n_in,
                              void* d_out, int out_size, void* d_ws, size_t ws_size,
                              hipStream_t stream) {
  const float* p  = (const float*)d_in[0];
  const float* W  = (const float*)d_in[1];
  const float* bb = (const float*)d_in[2];
  float* out = (float*)d_out;

  const int n = in_sizes[0] / 3;   // 16384

  // ws layout:
  //   c_all @ 0     : 3*2048 ints  (bin ENDS, query prefix sums)
  //   s_all @ 24KB  : 3*n float4   (sorted arrays)
  int*    c_all = (int*)d_ws;
  float4* s_all = (float4*)((char*)d_ws + 3 * NBINS * 4);
  int*    cx = c_all;
  int*    cy = cx + NBINS;
  int*    cz = cy + NBINS;
  float4* sx = s_all;
  float4* sy = sx + n;
  float4* sz = sy + n;

  sort_kernel<<<3 * PARTS, 1024, 0, stream>>>(p, c_all, s_all, n);
  // 2 queries per wave, 4 waves per block -> n/8 blocks
  query_kernel<<<n / 8, BLOCK, 0, stream>>>(sx, sy, sz, cx, cy, cz, W, bb, out, n);
}

// Round 6
// 120.037 us; speedup vs baseline: 1.0797x; 1.0797x over previous
//
#include <hip/hip_runtime.h>
#include <math.h>

// n=16384 Gaussian points in 3D. Exact 12-NN (incl self) per point:
//   out[i] = b + ( (W·p_i)·(1 + 11/sqrt(2)) + 0.5 * sum_{11NN} W·|p_i - p_j| ) / 12
//
// R20: revert R19's dual-query (regressed: +12% insts, busy flat -> kernel is
// memory-LATENCY bound, not dep-bound). R18 structure + MLP fix: VGPR was 36
// (compiler default occupancy target) -> only ~4 outstanding float4 loads/lane;
// ~25 serial L2-gather batches x ~200cy dominates (VALUBusy 48%).
//   - __launch_bounds__(BLOCK, 1): unlock VGPRs (trade waves for ILP)
//   - seed: batch-load all 12 float4 into regs BEFORE arithmetic (4 min-chains)
//   - collect: unroll x4, 4-load batch then 4 process steps
// Sort unchanged (R18: one self-sufficient plain dispatch, <15 µs).
//
// Per query: best-axis slab; seed 768 around bin-estimated rank -> u = 12th
// of 64 lane minima (valid UB of tau) -> extent from prefix sums -> collect
// into 4-deep paired (d2,w) queue -> 12-round paired knockout (exact take-12,
// first-lane tie-break) -> reduce. Rare overflow (wave-uniform) -> exact med3
// fallback over the same extent. Self contributes w=0.

#define NBINS  2048
#define PARTS  16
#define CMIN_  (-6.0f)
#define INVBW_ ((float)NBINS / 12.0f)
#define BLOCK  256
#define WPB    4
#define SEED   768
#define KK     12
#define CD     4
#define BIG    3.0e38f

__device__ __forceinline__ int bin_of(float x) {
  int b = (int)((x - CMIN_) * INVBW_);
  b = b < 0 ? 0 : b;
  b = b > NBINS - 1 ? NBINS - 1 : b;
  return b;
}

__device__ __forceinline__ float wave_min(float v) {
#pragma unroll
  for (int o = 1; o < 64; o <<= 1) v = fminf(v, __shfl_xor(v, o));
  return v;
}

// sorted ascending 4-deep paired insert (static indexing -> registers)
__device__ __forceinline__ void ins4(float (&qd)[CD], float (&qw)[CD],
                                     float d, float w) {
#pragma unroll
  for (int k = CD - 1; k >= 1; --k) {
    const bool up  = (qd[k - 1] > d);
    const bool mid = (qd[k] > d);
    const float nd = up ? qd[k - 1] : (mid ? d : qd[k]);
    const float nw = up ? qw[k - 1] : (mid ? w : qw[k]);
    qd[k] = nd; qw[k] = nw;
  }
  if (qd[0] > d) { qw[0] = w; qd[0] = d; }
}

// ---------------- K1: self-sufficient fused sort (grid = 3*PARTS, plain) ----
__global__ __launch_bounds__(1024)
void sort_kernel(const float* __restrict__ p, int* __restrict__ c_all,
                 float4* __restrict__ s_all, int n) {
  __shared__ int h_all[NBINS];   // full per-axis histogram
  __shared__ int h_pre[NBINS];   // hist of indices < myStart; later: cursors
  __shared__ int wsum[16];
  const int tid  = threadIdx.x;
  const int dim  = blockIdx.x / PARTS;
  const int part = blockIdx.x % PARTS;
  const int chunk   = (n + PARTS - 1) / PARTS;
  const int myStart = part * chunk;
  const int myEnd   = min(myStart + chunk, n);

  h_all[tid] = 0; h_all[tid + 1024] = 0;
  h_pre[tid] = 0; h_pre[tid + 1024] = 0;
  __syncthreads();

  for (int i = tid; i < n; i += 1024) {
    const int b = bin_of(p[3 * i + dim]);
    atomicAdd(&h_all[b], 1);
    if (i < myStart) atomicAdd(&h_pre[b], 1);   // wave-uniform predicate
  }
  __syncthreads();

  const int a = h_all[2 * tid], b = h_all[2 * tid + 1];
  const int v = a + b;
  const int lane = tid & 63, wid = tid >> 6;     // 16 waves
  int incl = v;
#pragma unroll
  for (int o = 1; o < 64; o <<= 1) {
    const int t = __shfl_up(incl, o);
    if (lane >= o) incl += t;
  }
  if (lane == 63) wsum[wid] = incl;
  __syncthreads();
  int woff = 0;
  for (int wI = 0; wI < wid; ++wI) woff += wsum[wI];   // broadcast reads
  const int excl = woff + incl - v;                    // start of bin 2*tid

  if (part == 0) {
    int* __restrict__ cursor = c_all + (size_t)dim * NBINS;
    cursor[2 * tid]     = excl + a;
    cursor[2 * tid + 1] = excl + a + b;
  }

  const int c0 = excl + h_pre[2 * tid];
  const int c1 = excl + a + h_pre[2 * tid + 1];
  __syncthreads();
  h_pre[2 * tid]     = c0;
  h_pre[2 * tid + 1] = c1;
  __syncthreads();

  float4* __restrict__ sorted = s_all + (size_t)dim * n;
  for (int i = myStart + tid; i < myEnd; i += 1024) {
    const float x = p[3 * i], y = p[3 * i + 1], z = p[3 * i + 2];
    const float c = (dim == 0) ? x : (dim == 1) ? y : z;
    const int pos = atomicAdd(&h_pre[bin_of(c)], 1);
    sorted[pos] = make_float4(x, y, z, __int_as_float(i));
  }
}

// ---------------- K2: query (one wave per query, best-axis extent) -----------
__global__ __launch_bounds__(BLOCK, 1)
void query_kernel(const float4* __restrict__ sx, const float4* __restrict__ sy,
                  const float4* __restrict__ sz, const int* __restrict__ cx,
                  const int* __restrict__ cy, const int* __restrict__ cz,
                  const float* __restrict__ W, const float* __restrict__ bias,
                  float* __restrict__ out, int n) {
  const int lane = threadIdx.x & 63;
  const int wv   = threadIdx.x >> 6;
  const int t    = wv * (n >> 2) + blockIdx.x;     // quartile interleave
  const float W0 = W[0], W1 = W[1], W2 = W[2];
  const float bb = bias[0];

  const float4 me = sx[t];                          // enumerate via x-sorted
  const float xi = me.x, yi = me.y, zi = me.z;
  const int orig = __float_as_int(me.w);

  // ---- choose axis with max |coord| (wave-uniform) ----
  const float ax = fabsf(xi), ay = fabsf(yi), az = fabsf(zi);
  const float4* sv; const int* cur; float cq;
  if (ay >= ax && ay >= az)      { sv = sy; cur = cy; cq = yi; }
  else if (az >= ax && az >= ay) { sv = sz; cur = cz; cq = zi; }
  else                           { sv = sx; cur = cx; cq = xi; }

  // ---- bin-estimated rank -> seed window ----
  const int bq = bin_of(cq);
  const int bs = (bq > 0) ? cur[bq - 1] : 0;
  const int be = cur[bq];
  int lo = ((bs + be) >> 1) - SEED / 2;
  lo = lo < 0 ? 0 : lo;
  lo = lo > n - SEED ? n - SEED : lo;
  const float4* base = sv + lo + lane;

  // ---- 1. seed lane-minima: batch-load ALL 12 first (MLP), then 4 chains ----
  float4 cs[SEED / 64];
#pragma unroll
  for (int s = 0; s < SEED / 64; ++s) cs[s] = base[s * 64];
  float m0 = BIG, m1 = BIG, m2 = BIG, m3 = BIG;
#pragma unroll
  for (int s = 0; s < SEED / 64; s += 4) {
    {
      const float dx = xi - cs[s].x, dy = yi - cs[s].y, dz = zi - cs[s].z;
      m0 = fminf(m0, fmaf(dx, dx, fmaf(dy, dy, dz * dz)));
    }
    {
      const float dx = xi - cs[s + 1].x, dy = yi - cs[s + 1].y, dz = zi - cs[s + 1].z;
      m1 = fminf(m1, fmaf(dx, dx, fmaf(dy, dy, dz * dz)));
    }
    {
      const float dx = xi - cs[s + 2].x, dy = yi - cs[s + 2].y, dz = zi - cs[s + 2].z;
      m2 = fminf(m2, fmaf(dx, dx, fmaf(dy, dy, dz * dz)));
    }
    {
      const float dx = xi - cs[s + 3].x, dy = yi - cs[s + 3].y, dz = zi - cs[s + 3].z;
      m3 = fminf(m3, fmaf(dx, dx, fmaf(dy, dy, dz * dz)));
    }
  }
  const float m = fminf(fminf(m0, m1), fminf(m2, m3));

  // ---- 2. u = 12th smallest of the 64 lane minima ----
  float u;
  {
    float v = m;
#pragma unroll
    for (int r = 0; r < KK; ++r) {
      const float mm = wave_min(v);
      u = mm;
      v = (v == mm) ? BIG : v;
    }
  }

  // ---- 3. extent from prefix sums: {|c - cq| <= sqrt(u)} ⊆ [lo2, hi2) ----
  const float s = sqrtf(u);
  const int bl = bin_of(cq - s);
  const int bh = bin_of(cq + s);
  const int lo2 = (bl > 0) ? cur[bl - 1] : 0;
  const int hi2 = cur[bh];
  const int len   = hi2 - lo2;
  const int full  = len >> 6;             // complete 64-chunks
  const int steps = (len + 63) >> 6;

  // ---- collect-scan: x4 unrolled batch-load, full chunks unguarded ----
  float qd[CD], qw[CD];
  int ccnt = 0;
#pragma unroll
  for (int k = 0; k < CD; ++k) { qd[k] = BIG; qw[k] = 0.f; }

#define PROC1(c)                                                              \
  {                                                                           \
    const float dx = xi - (c).x, dy = yi - (c).y, dz = zi - (c).z;            \
    const float d2 = fmaf(dx, dx, fmaf(dy, dy, dz * dz));                     \
    if (d2 <= u) {                                                            \
      const float w = fmaf(W0, fabsf(dx), fmaf(W1, fabsf(dy), W2 * fabsf(dz)));\
      ++ccnt; ins4(qd, qw, d2, w);                                            \
    }                                                                         \
  }

  const float4* cbase = sv + lo2 + lane;
  int st = 0;
  for (; st + 4 <= full; st += 4) {
    const float4 c0 = cbase[(st + 0) * 64];
    const float4 c1 = cbase[(st + 1) * 64];
    const float4 c2 = cbase[(st + 2) * 64];
    const float4 c3 = cbase[(st + 3) * 64];
    PROC1(c0) PROC1(c1) PROC1(c2) PROC1(c3)
  }
  for (; st < full; ++st) {
    const float4 c = cbase[st * 64];
    PROC1(c)
  }
  if (st < steps) {                        // partial last chunk
    const int pos = lo2 + st * 64 + lane;
    if (pos < hi2) {
      const float4 c = sv[pos];
      PROC1(c)
    }
  }
#undef PROC1

  // ---- 4. extract exact 12 smallest ----
  float acc = 0.f;
  const bool ovf = __ballot(ccnt > CD) != 0ULL;   // wave-uniform
  if (!ovf) {
#pragma unroll
    for (int r = 0; r < KK; ++r) {
      const float mm = wave_min(qd[0]);
      const unsigned long long bal = __ballot(qd[0] == mm);
      if (qd[0] == mm && lane == (int)(__ffsll(bal) - 1)) {
        acc += qw[0];
#pragma unroll
        for (int k = 0; k < CD - 1; ++k) { qd[k] = qd[k + 1]; qw[k] = qw[k + 1]; }
        qd[CD - 1] = BIG;
      }
    }
  } else {
    // rare exact fallback over the same extent: med3 top-12 -> tau -> rescan
    float dd[KK];
#pragma unroll
    for (int k = 0; k < KK; ++k) dd[k] = BIG;
    for (int s0 = 0; s0 < steps; ++s0) {
      const int pos = lo2 + s0 * 64 + lane;
      const float4 c = sv[(pos < hi2) ? pos : hi2 - 1];
      const float dx = xi - c.x, dy = yi - c.y, dz = zi - c.z;
      const float d2 = (pos < hi2) ? fmaf(dx, dx, fmaf(dy, dy, dz * dz)) : BIG;
#pragma unroll
      for (int k = KK - 1; k >= 1; --k)
        dd[k] = __builtin_amdgcn_fmed3f(d2, dd[k - 1], dd[k]);
      dd[0] = fminf(dd[0], d2);
    }
    float tau = 0.f;
#pragma unroll
    for (int r = 0; r < KK; ++r) {
      const float mm = wave_min(dd[0]);
      if (dd[0] == mm) {
#pragma unroll
        for (int k = 0; k < KK - 1; ++k) dd[k] = dd[k + 1];
        dd[KK - 1] = BIG;
      }
      tau = mm;
    }
    for (int s0 = 0; s0 < steps; ++s0) {
      const int pos = lo2 + s0 * 64 + lane;
      if (pos < hi2) {
        const float4 c = sv[pos];
        const float dx = xi - c.x, dy = yi - c.y, dz = zi - c.z;
        const float d2 = fmaf(dx, dx, fmaf(dy, dy, dz * dz));
        const float w  = fmaf(W0, fabsf(dx), fmaf(W1, fabsf(dy), W2 * fabsf(dz)));
        acc += (d2 <= tau) ? w : 0.f;
      }
    }
  }

  // ---- 5. reduce + write ----
#pragma unroll
  for (int o = 1; o < 64; o <<= 1) acc += __shfl_xor(acc, o);
  if (lane == 0) {
    const float xw0 = W0 * xi + W1 * yi + W2 * zi;
    // 1 + 11/sqrt(2)
    out[orig] = bb + (xw0 * 8.778174593052022f + 0.5f * acc) * (1.0f / 12.0f);
  }
}

extern "C" void kernel_launch(void* const* d_in, const int* in_sizes, int n_in,
                              void* d_out, int out_size, void* d_ws, size_t ws_size,
                              hipStream_t stream) {
  const float* p  = (const float*)d_in[0];
  const float* W  = (const float*)d_in[1];
  const float* bb = (const float*)d_in[2];
  float* out = (float*)d_out;

  const int n = in_sizes[0] / 3;   // 16384

  // ws layout:
  //   c_all @ 0     : 3*2048 ints  (bin ENDS, query prefix sums)
  //   s_all @ 24KB  : 3*n float4   (sorted arrays)
  int*    c_all = (int*)d_ws;
  float4* s_all = (float4*)((char*)d_ws + 3 * NBINS * 4);
  int*    cx = c_all;
  int*    cy = cx + NBINS;
  int*    cz = cy + NBINS;
  float4* sx = s_all;
  float4* sy = sx + n;
  float4* sz = sy + n;

  sort_kernel<<<3 * PARTS, 1024, 0, stream>>>(p, c_all, s_all, n);
  query_kernel<<<n / WPB, BLOCK, 0, stream>>>(sx, sy, sz, cx, cy, cz, W, bb, out, n);
}

// Round 7
// 115.196 us; speedup vs baseline: 1.1251x; 1.0420x over previous
//
#include <hip/hip_runtime.h>
#include <math.h>

// n=16384 Gaussian points in 3D. Exact 12-NN (incl self) per point:
//   out[i] = b + ( (W·p_i)·(1 + 11/sqrt(2)) + 0.5 * sum_{11NN} W·|p_i - p_j| ) / 12
//
// R21: R20's MLP attempt was silently rolled back by the compiler (VGPR
// stayed 36 -> loads never went deep in flight; VALUBusy stuck at 50%).
// This round forces the pipeline at source level:
//   - seed: 12-register preload PINNED with sched_barrier(0) after the load
//     group (all 12 loads issue before any FMA; compiler cannot re-roll).
//   - collect: A/B double-buffered pipeline (load group g+1, process group g),
//     loads address-clamped + validity-masked so they are unconditional.
//   - u-phase: 12-round knockout (72 serial shfls, exact 12th) replaced by
//     10-iter ballot bisection maintaining a VALID upper bound of tau
//     (popcll(ballot(m<=hi)) >= 12  =>  >=12 points within hi). Extraction
//     knockout (exactness-critical) unchanged.
// Sort unchanged (R18: one self-sufficient plain dispatch, <15 µs).
//
// Per query: best-axis slab; seed 768 around bin-estimated rank -> u (UB of
// tau) -> extent from prefix sums -> collect into 4-deep paired (d2,w) queue
// -> 12-round paired knockout (exact take-12, first-lane tie-break) ->
// reduce. Rare overflow (wave-uniform) -> exact med3 fallback over the same
// extent. Self contributes w=0.

#define NBINS  2048
#define PARTS  16
#define CMIN_  (-6.0f)
#define INVBW_ ((float)NBINS / 12.0f)
#define BLOCK  256
#define WPB    4
#define SEED   768
#define KK     12
#define CD     4
#define BIG    3.0e38f

__device__ __forceinline__ int bin_of(float x) {
  int b = (int)((x - CMIN_) * INVBW_);
  b = b < 0 ? 0 : b;
  b = b > NBINS - 1 ? NBINS - 1 : b;
  return b;
}

__device__ __forceinline__ float wave_min(float v) {
#pragma unroll
  for (int o = 1; o < 64; o <<= 1) v = fminf(v, __shfl_xor(v, o));
  return v;
}

// sorted ascending 4-deep paired insert (static indexing -> registers)
__device__ __forceinline__ void ins4(float (&qd)[CD], float (&qw)[CD],
                                     float d, float w) {
#pragma unroll
  for (int k = CD - 1; k >= 1; --k) {
    const bool up  = (qd[k - 1] > d);
    const bool mid = (qd[k] > d);
    const float nd = up ? qd[k - 1] : (mid ? d : qd[k]);
    const float nw = up ? qw[k - 1] : (mid ? w : qw[k]);
    qd[k] = nd; qw[k] = nw;
  }
  if (qd[0] > d) { qw[0] = w; qd[0] = d; }
}

// ---------------- K1: self-sufficient fused sort (grid = 3*PARTS, plain) ----
__global__ __launch_bounds__(1024)
void sort_kernel(const float* __restrict__ p, int* __restrict__ c_all,
                 float4* __restrict__ s_all, int n) {
  __shared__ int h_all[NBINS];   // full per-axis histogram
  __shared__ int h_pre[NBINS];   // hist of indices < myStart; later: cursors
  __shared__ int wsum[16];
  const int tid  = threadIdx.x;
  const int dim  = blockIdx.x / PARTS;
  const int part = blockIdx.x % PARTS;
  const int chunk   = (n + PARTS - 1) / PARTS;
  const int myStart = part * chunk;
  const int myEnd   = min(myStart + chunk, n);

  h_all[tid] = 0; h_all[tid + 1024] = 0;
  h_pre[tid] = 0; h_pre[tid + 1024] = 0;
  __syncthreads();

  for (int i = tid; i < n; i += 1024) {
    const int b = bin_of(p[3 * i + dim]);
    atomicAdd(&h_all[b], 1);
    if (i < myStart) atomicAdd(&h_pre[b], 1);   // wave-uniform predicate
  }
  __syncthreads();

  const int a = h_all[2 * tid], b = h_all[2 * tid + 1];
  const int v = a + b;
  const int lane = tid & 63, wid = tid >> 6;     // 16 waves
  int incl = v;
#pragma unroll
  for (int o = 1; o < 64; o <<= 1) {
    const int t = __shfl_up(incl, o);
    if (lane >= o) incl += t;
  }
  if (lane == 63) wsum[wid] = incl;
  __syncthreads();
  int woff = 0;
  for (int wI = 0; wI < wid; ++wI) woff += wsum[wI];   // broadcast reads
  const int excl = woff + incl - v;                    // start of bin 2*tid

  if (part == 0) {
    int* __restrict__ cursor = c_all + (size_t)dim * NBINS;
    cursor[2 * tid]     = excl + a;
    cursor[2 * tid + 1] = excl + a + b;
  }

  const int c0 = excl + h_pre[2 * tid];
  const int c1 = excl + a + h_pre[2 * tid + 1];
  __syncthreads();
  h_pre[2 * tid]     = c0;
  h_pre[2 * tid + 1] = c1;
  __syncthreads();

  float4* __restrict__ sorted = s_all + (size_t)dim * n;
  for (int i = myStart + tid; i < myEnd; i += 1024) {
    const float x = p[3 * i], y = p[3 * i + 1], z = p[3 * i + 2];
    const float c = (dim == 0) ? x : (dim == 1) ? y : z;
    const int pos = atomicAdd(&h_pre[bin_of(c)], 1);
    sorted[pos] = make_float4(x, y, z, __int_as_float(i));
  }
}

// ---------------- K2: query (one wave per query, best-axis extent) -----------
__global__ __launch_bounds__(BLOCK, 1)
void query_kernel(const float4* __restrict__ sx, const float4* __restrict__ sy,
                  const float4* __restrict__ sz, const int* __restrict__ cx,
                  const int* __restrict__ cy, const int* __restrict__ cz,
                  const float* __restrict__ W, const float* __restrict__ bias,
                  float* __restrict__ out, int n) {
  const int lane = threadIdx.x & 63;
  const int wv   = threadIdx.x >> 6;
  const int t    = wv * (n >> 2) + blockIdx.x;     // quartile interleave
  const float W0 = W[0], W1 = W[1], W2 = W[2];
  const float bb = bias[0];

  const float4 me = sx[t];                          // enumerate via x-sorted
  const float xi = me.x, yi = me.y, zi = me.z;
  const int orig = __float_as_int(me.w);

  // ---- choose axis with max |coord| (wave-uniform) ----
  const float ax = fabsf(xi), ay = fabsf(yi), az = fabsf(zi);
  const float4* sv; const int* cur; float cq;
  if (ay >= ax && ay >= az)      { sv = sy; cur = cy; cq = yi; }
  else if (az >= ax && az >= ay) { sv = sz; cur = cz; cq = zi; }
  else                           { sv = sx; cur = cx; cq = xi; }

  // ---- bin-estimated rank -> seed window ----
  const int bq = bin_of(cq);
  const int bs = (bq > 0) ? cur[bq - 1] : 0;
  const int be = cur[bq];
  int lo = ((bs + be) >> 1) - SEED / 2;
  lo = lo < 0 ? 0 : lo;
  lo = lo > n - SEED ? n - SEED : lo;
  const float4* base = sv + lo + lane;

  // ---- 1. seed lane-minima: 12 loads PINNED before any arithmetic ----
  float4 cs[SEED / 64];
#pragma unroll
  for (int s = 0; s < SEED / 64; ++s) cs[s] = base[s * 64];
  __builtin_amdgcn_sched_barrier(0);   // all 12 loads issue first (force MLP)
  float m0 = BIG, m1 = BIG, m2 = BIG, m3 = BIG;
#pragma unroll
  for (int s = 0; s < SEED / 64; s += 4) {
    {
      const float dx = xi - cs[s].x, dy = yi - cs[s].y, dz = zi - cs[s].z;
      m0 = fminf(m0, fmaf(dx, dx, fmaf(dy, dy, dz * dz)));
    }
    {
      const float dx = xi - cs[s + 1].x, dy = yi - cs[s + 1].y, dz = zi - cs[s + 1].z;
      m1 = fminf(m1, fmaf(dx, dx, fmaf(dy, dy, dz * dz)));
    }
    {
      const float dx = xi - cs[s + 2].x, dy = yi - cs[s + 2].y, dz = zi - cs[s + 2].z;
      m2 = fminf(m2, fmaf(dx, dx, fmaf(dy, dy, dz * dz)));
    }
    {
      const float dx = xi - cs[s + 3].x, dy = yi - cs[s + 3].y, dz = zi - cs[s + 3].z;
      m3 = fminf(m3, fmaf(dx, dx, fmaf(dy, dy, dz * dz)));
    }
  }
  const float m = fminf(fminf(m0, m1), fminf(m2, m3));

  // ---- 2. u = valid UB of tau via ballot bisection (10 iters) ----
  // invariant: popcll(ballot(m <= hi)) >= 12  =>  >=12 points within hi.
  float u;
  {
    float hiv = m;
#pragma unroll
    for (int o = 1; o < 64; o <<= 1) hiv = fmaxf(hiv, __shfl_xor(hiv, o));
    float lov = 0.f;
#pragma unroll
    for (int it = 0; it < 10; ++it) {
      const float mid = 0.5f * (lov + hiv);
      const int cnt = __popcll(__ballot(m <= mid));
      if (cnt >= KK) hiv = mid; else lov = mid;
    }
    u = hiv;
  }

  // ---- 3. extent from prefix sums: {|c - cq| <= sqrt(u)} ⊆ [lo2, hi2) ----
  const float s = sqrtf(u);
  const int bl = bin_of(cq - s);
  const int bh = bin_of(cq + s);
  const int lo2 = (bl > 0) ? cur[bl - 1] : 0;
  const int hi2 = cur[bh];
  const int len   = hi2 - lo2;
  const int nch   = (len + 63) >> 6;      // 64-chunks (>=1: window has self)
  const int steps = nch;

  // ---- collect-scan: A/B double-buffered pipeline, masked clamped loads ----
  float qd[CD], qw[CD];
  int ccnt = 0;
#pragma unroll
  for (int k = 0; k < CD; ++k) { qd[k] = BIG; qw[k] = 0.f; }

#define LD1(cix) (sv[lo2 + min((cix) * 64 + lane, len - 1)])
#define PROCC(cc, cix)                                                        \
  {                                                                           \
    const float dx = xi - (cc).x, dy = yi - (cc).y, dz = zi - (cc).z;         \
    float d2 = fmaf(dx, dx, fmaf(dy, dy, dz * dz));                           \
    d2 = ((cix) * 64 + lane < len) ? d2 : BIG;                                \
    if (d2 <= u) {                                                            \
      const float w = fmaf(W0, fabsf(dx), fmaf(W1, fabsf(dy), W2 * fabsf(dz)));\
      ++ccnt; ins4(qd, qw, d2, w);                                            \
    }                                                                         \
  }

  {
    float4 A0 = LD1(0), A1 = LD1(1), A2 = LD1(2), A3 = LD1(3);
    float4 B0, B1, B2, B3;
    int c = 0;
    for (;;) {
      B0 = LD1(c + 4); B1 = LD1(c + 5); B2 = LD1(c + 6); B3 = LD1(c + 7);
      PROCC(A0, c) PROCC(A1, c + 1) PROCC(A2, c + 2) PROCC(A3, c + 3)
      c += 4;
      if (c >= nch) break;
      A0 = LD1(c + 4); A1 = LD1(c + 5); A2 = LD1(c + 6); A3 = LD1(c + 7);
      PROCC(B0, c) PROCC(B1, c + 1) PROCC(B2, c + 2) PROCC(B3, c + 3)
      c += 4;
      if (c >= nch) break;
    }
  }
#undef LD1
#undef PROCC

  // ---- 4. extract exact 12 smallest ----
  float acc = 0.f;
  const bool ovf = __ballot(ccnt > CD) != 0ULL;   // wave-uniform
  if (!ovf) {
#pragma unroll
    for (int r = 0; r < KK; ++r) {
      const float mm = wave_min(qd[0]);
      const unsigned long long bal = __ballot(qd[0] == mm);
      if (qd[0] == mm && lane == (int)(__ffsll(bal) - 1)) {
        acc += qw[0];
#pragma unroll
        for (int k = 0; k < CD - 1; ++k) { qd[k] = qd[k + 1]; qw[k] = qw[k + 1]; }
        qd[CD - 1] = BIG;
      }
    }
  } else {
    // rare exact fallback over the same extent: med3 top-12 -> tau -> rescan
    float dd[KK];
#pragma unroll
    for (int k = 0; k < KK; ++k) dd[k] = BIG;
    for (int s0 = 0; s0 < steps; ++s0) {
      const int pos = lo2 + s0 * 64 + lane;
      const float4 c = sv[(pos < hi2) ? pos : hi2 - 1];
      const float dx = xi - c.x, dy = yi - c.y, dz = zi - c.z;
      const float d2 = (pos < hi2) ? fmaf(dx, dx, fmaf(dy, dy, dz * dz)) : BIG;
#pragma unroll
      for (int k = KK - 1; k >= 1; --k)
        dd[k] = __builtin_amdgcn_fmed3f(d2, dd[k - 1], dd[k]);
      dd[0] = fminf(dd[0], d2);
    }
    float tau = 0.f;
#pragma unroll
    for (int r = 0; r < KK; ++r) {
      const float mm = wave_min(dd[0]);
      if (dd[0] == mm) {
#pragma unroll
        for (int k = 0; k < KK - 1; ++k) dd[k] = dd[k + 1];
        dd[KK - 1] = BIG;
      }
      tau = mm;
    }
    for (int s0 = 0; s0 < steps; ++s0) {
      const int pos = lo2 + s0 * 64 + lane;
      if (pos < hi2) {
        const float4 c = sv[pos];
        const float dx = xi - c.x, dy = yi - c.y, dz = zi - c.z;
        const float d2 = fmaf(dx, dx, fmaf(dy, dy, dz * dz));
        const float w  = fmaf(W0, fabsf(dx), fmaf(W1, fabsf(dy), W2 * fabsf(dz)));
        acc += (d2 <= tau) ? w : 0.f;
      }
    }
  }

  // ---- 5. reduce + write ----
#pragma unroll
  for (int o = 1; o < 64; o <<= 1) acc += __shfl_xor(acc, o);
  if (lane == 0) {
    const float xw0 = W0 * xi + W1 * yi + W2 * zi;
    // 1 + 11/sqrt(2)
    out[orig] = bb + (xw0 * 8.778174593052022f + 0.5f * acc) * (1.0f / 12.0f);
  }
}

extern "C" void kernel_launch(void* const* d_in, const int* in_sizes, int n_in,
                              void* d_out, int out_size, void* d_ws, size_t ws_size,
                              hipStream_t stream) {
  const float* p  = (const float*)d_in[0];
  const float* W  = (const float*)d_in[1];
  const float* bb = (const float*)d_in[2];
  float* out = (float*)d_out;

  const int n = in_sizes[0] / 3;   // 16384

  // ws layout:
  //   c_all @ 0     : 3*2048 ints  (bin ENDS, query prefix sums)
  //   s_all @ 24KB  : 3*n float4   (sorted arrays)
  int*    c_all = (int*)d_ws;
  float4* s_all = (float4*)((char*)d_ws + 3 * NBINS * 4);
  int*    cx = c_all;
  int*    cy = cx + NBINS;
  int*    cz = cy + NBINS;
  float4* sx = s_all;
  float4* sy = sx + n;
  float4* sz = sy + n;

  sort_kernel<<<3 * PARTS, 1024, 0, stream>>>(p, c_all, s_all, n);
  query_kernel<<<n / WPB, BLOCK, 0, stream>>>(sx, sy, sz, cx, cy, cz, W, bb, out, n);
}

// Round 8
// 109.610 us; speedup vs baseline: 1.1824x; 1.0510x over previous
//
#include <hip/hip_runtime.h>
#include <math.h>

// n=16384 Gaussian points in 3D. Exact 12-NN (incl self) per point:
//   out[i] = b + ( (W·p_i)·(1 + 11/sqrt(2)) + 0.5 * sum_{11NN} W·|p_i - p_j| ) / 12
//
// R22: fuse seed scan + collect scan (they covered ~the same ~800 points:
// 12 seed chunks + ~13 extent chunks -> ~25 load batches/query). Now:
//   - seed scan inserts ALL 768 window points into the 4-deep per-lane
//     (d2,w) queue unconditionally (ins4 is branchless cndmask), tracking
//     ev = min(ev, max(d2, qd[3])) = lane's 5th-smallest-seen watermark.
//   - lane minima for the u-bisection = qd[0]; u = valid UB of tau via
//     10-iter ballot bisection (R21).
//   - collect scans ONLY the extent tails outside the seed window
//     (typically 1-3 chunks). ~15 load batches/query total (-40%).
//   - exactness: after 12-round extraction, tau = 12th extracted; if any
//     lane ev <= tau a candidate may have been evicted -> exact med3
//     fallback over the full extent (self-contained, unchanged). Seed
//     points outside the extent have d2 > u >= tau: never in top-12,
//     never corrupt ev below tau.
// Sort unchanged (R18: one self-sufficient plain dispatch, <15 µs).

#define NBINS  2048
#define PARTS  16
#define CMIN_  (-6.0f)
#define INVBW_ ((float)NBINS / 12.0f)
#define BLOCK  256
#define WPB    4
#define SEED   768
#define KK     12
#define CD     4
#define BIG    3.0e38f

__device__ __forceinline__ int bin_of(float x) {
  int b = (int)((x - CMIN_) * INVBW_);
  b = b < 0 ? 0 : b;
  b = b > NBINS - 1 ? NBINS - 1 : b;
  return b;
}

__device__ __forceinline__ float wave_min(float v) {
#pragma unroll
  for (int o = 1; o < 64; o <<= 1) v = fminf(v, __shfl_xor(v, o));
  return v;
}

// sorted ascending 4-deep paired insert (static indexing -> registers,
// fully branchless cndmask chain)
__device__ __forceinline__ void ins4(float (&qd)[CD], float (&qw)[CD],
                                     float d, float w) {
#pragma unroll
  for (int k = CD - 1; k >= 1; --k) {
    const bool up  = (qd[k - 1] > d);
    const bool mid = (qd[k] > d);
    const float nd = up ? qd[k - 1] : (mid ? d : qd[k]);
    const float nw = up ? qw[k - 1] : (mid ? w : qw[k]);
    qd[k] = nd; qw[k] = nw;
  }
  if (qd[0] > d) { qw[0] = w; qd[0] = d; }
}

// ---------------- K1: self-sufficient fused sort (grid = 3*PARTS, plain) ----
__global__ __launch_bounds__(1024)
void sort_kernel(const float* __restrict__ p, int* __restrict__ c_all,
                 float4* __restrict__ s_all, int n) {
  __shared__ int h_all[NBINS];   // full per-axis histogram
  __shared__ int h_pre[NBINS];   // hist of indices < myStart; later: cursors
  __shared__ int wsum[16];
  const int tid  = threadIdx.x;
  const int dim  = blockIdx.x / PARTS;
  const int part = blockIdx.x % PARTS;
  const int chunk   = (n + PARTS - 1) / PARTS;
  const int myStart = part * chunk;
  const int myEnd   = min(myStart + chunk, n);

  h_all[tid] = 0; h_all[tid + 1024] = 0;
  h_pre[tid] = 0; h_pre[tid + 1024] = 0;
  __syncthreads();

  for (int i = tid; i < n; i += 1024) {
    const int b = bin_of(p[3 * i + dim]);
    atomicAdd(&h_all[b], 1);
    if (i < myStart) atomicAdd(&h_pre[b], 1);   // wave-uniform predicate
  }
  __syncthreads();

  const int a = h_all[2 * tid], b = h_all[2 * tid + 1];
  const int v = a + b;
  const int lane = tid & 63, wid = tid >> 6;     // 16 waves
  int incl = v;
#pragma unroll
  for (int o = 1; o < 64; o <<= 1) {
    const int t = __shfl_up(incl, o);
    if (lane >= o) incl += t;
  }
  if (lane == 63) wsum[wid] = incl;
  __syncthreads();
  int woff = 0;
  for (int wI = 0; wI < wid; ++wI) woff += wsum[wI];   // broadcast reads
  const int excl = woff + incl - v;                    // start of bin 2*tid

  if (part == 0) {
    int* __restrict__ cursor = c_all + (size_t)dim * NBINS;
    cursor[2 * tid]     = excl + a;
    cursor[2 * tid + 1] = excl + a + b;
  }

  const int c0 = excl + h_pre[2 * tid];
  const int c1 = excl + a + h_pre[2 * tid + 1];
  __syncthreads();
  h_pre[2 * tid]     = c0;
  h_pre[2 * tid + 1] = c1;
  __syncthreads();

  float4* __restrict__ sorted = s_all + (size_t)dim * n;
  for (int i = myStart + tid; i < myEnd; i += 1024) {
    const float x = p[3 * i], y = p[3 * i + 1], z = p[3 * i + 2];
    const float c = (dim == 0) ? x : (dim == 1) ? y : z;
    const int pos = atomicAdd(&h_pre[bin_of(c)], 1);
    sorted[pos] = make_float4(x, y, z, __int_as_float(i));
  }
}

// ---------------- K2: query (one wave per query, fused seed+collect) --------
__global__ __launch_bounds__(BLOCK, 1)
void query_kernel(const float4* __restrict__ sx, const float4* __restrict__ sy,
                  const float4* __restrict__ sz, const int* __restrict__ cx,
                  const int* __restrict__ cy, const int* __restrict__ cz,
                  const float* __restrict__ W, const float* __restrict__ bias,
                  float* __restrict__ out, int n) {
  const int lane = threadIdx.x & 63;
  const int wv   = threadIdx.x >> 6;
  const int t    = wv * (n >> 2) + blockIdx.x;     // quartile interleave
  const float W0 = W[0], W1 = W[1], W2 = W[2];
  const float bb = bias[0];

  const float4 me = sx[t];                          // enumerate via x-sorted
  const float xi = me.x, yi = me.y, zi = me.z;
  const int orig = __float_as_int(me.w);

  // ---- choose axis with max |coord| (wave-uniform) ----
  const float ax = fabsf(xi), ay = fabsf(yi), az = fabsf(zi);
  const float4* sv; const int* cur; float cq;
  if (ay >= ax && ay >= az)      { sv = sy; cur = cy; cq = yi; }
  else if (az >= ax && az >= ay) { sv = sz; cur = cz; cq = zi; }
  else                           { sv = sx; cur = cx; cq = xi; }

  // ---- bin-estimated rank -> seed window ----
  const int bq = bin_of(cq);
  const int bs = (bq > 0) ? cur[bq - 1] : 0;
  const int be = cur[bq];
  int lo = ((bs + be) >> 1) - SEED / 2;
  lo = lo < 0 ? 0 : lo;
  lo = lo > n - SEED ? n - SEED : lo;
  const float4* base = sv + lo + lane;

  // queue + watermark
  float qd[CD], qw[CD];
  float ev = BIG;
#pragma unroll
  for (int k = 0; k < CD; ++k) { qd[k] = BIG; qw[k] = 0.f; }

  // process one candidate: branchless insert + watermark
#define PROCQ(cc, valid)                                                      \
  {                                                                           \
    const float dx = xi - (cc).x, dy = yi - (cc).y, dz = zi - (cc).z;         \
    float d2 = fmaf(dx, dx, fmaf(dy, dy, dz * dz));                           \
    d2 = (valid) ? d2 : BIG;                                                  \
    const float w = fmaf(W0, fabsf(dx), fmaf(W1, fabsf(dy), W2 * fabsf(dz))); \
    ev = fminf(ev, fmaxf(d2, qd[CD - 1]));                                    \
    ins4(qd, qw, d2, w);                                                      \
  }

  // ---- 1. seed scan: 12 pinned loads, unconditional queue inserts ----
  {
    float4 cs[SEED / 64];
#pragma unroll
    for (int s = 0; s < SEED / 64; ++s) cs[s] = base[s * 64];
    __builtin_amdgcn_sched_barrier(0);   // all 12 loads issue first (MLP)
#pragma unroll
    for (int s = 0; s < SEED / 64; ++s) PROCQ(cs[s], true)
  }

  // ---- 2. u = valid UB of tau via ballot bisection (m = qd[0]) ----
  float u;
  {
    const float m = qd[0];
    float hiv = m;
#pragma unroll
    for (int o = 1; o < 64; o <<= 1) hiv = fmaxf(hiv, __shfl_xor(hiv, o));
    float lov = 0.f;
#pragma unroll
    for (int it = 0; it < 10; ++it) {
      const float mid = 0.5f * (lov + hiv);
      const int cnt = __popcll(__ballot(m <= mid));
      if (cnt >= KK) hiv = mid; else lov = mid;
    }
    u = hiv;
  }

  // ---- 3. extent from prefix sums: {|c - cq| <= sqrt(u)} ⊆ [lo2, hi2) ----
  const float s = sqrtf(u);
  const int bl = bin_of(cq - s);
  const int bh = bin_of(cq + s);
  const int lo2 = (bl > 0) ? cur[bl - 1] : 0;
  const int hi2 = cur[bh];
  const int steps = (hi2 - lo2 + 63) >> 6;      // for fallback

  // ---- 4. tail scans: extent minus seed window ----
  {
    // left tail [lo2, min(hi2, lo))
    const int a0 = lo2, b0 = min(hi2, lo);
    const int len = b0 - a0;
    const int nch = (len + 63) >> 6;
    for (int c0 = 0; c0 < nch; ++c0) {
      const int idx = c0 * 64 + lane;
      const float4 c = sv[a0 + min(idx, len - 1)];
      PROCQ(c, idx < len)
    }
  }
  {
    // right tail [max(lo2, lo+SEED), hi2)
    const int a0 = max(lo2, lo + SEED), b0 = hi2;
    const int len = b0 - a0;
    const int nch = (len + 63) >> 6;
    for (int c0 = 0; c0 < nch; ++c0) {
      const int idx = c0 * 64 + lane;
      const float4 c = sv[a0 + min(idx, len - 1)];
      PROCQ(c, idx < len)
    }
  }
#undef PROCQ

  // ---- 5. extract exact 12 smallest; watermark check ----
  float acc = 0.f;
  float tau = 0.f;
#pragma unroll
  for (int r = 0; r < KK; ++r) {
    const float mm = wave_min(qd[0]);
    const unsigned long long bal = __ballot(qd[0] == mm);
    if (qd[0] == mm && lane == (int)(__ffsll(bal) - 1)) {
      acc += qw[0];
#pragma unroll
      for (int k = 0; k < CD - 1; ++k) { qd[k] = qd[k + 1]; qw[k] = qw[k + 1]; }
      qd[CD - 1] = BIG;
    }
    tau = mm;
  }

  const bool ovf = __ballot(ev <= tau) != 0ULL;   // wave-uniform
  if (ovf) {
    // rare exact fallback over the extent: med3 top-12 -> tau2 -> rescan
    float dd[KK];
#pragma unroll
    for (int k = 0; k < KK; ++k) dd[k] = BIG;
    for (int s0 = 0; s0 < steps; ++s0) {
      const int pos = lo2 + s0 * 64 + lane;
      const float4 c = sv[(pos < hi2) ? pos : hi2 - 1];
      const float dx = xi - c.x, dy = yi - c.y, dz = zi - c.z;
      const float d2 = (pos < hi2) ? fmaf(dx, dx, fmaf(dy, dy, dz * dz)) : BIG;
#pragma unroll
      for (int k = KK - 1; k >= 1; --k)
        dd[k] = __builtin_amdgcn_fmed3f(d2, dd[k - 1], dd[k]);
      dd[0] = fminf(dd[0], d2);
    }
    float tau2 = 0.f;
#pragma unroll
    for (int r = 0; r < KK; ++r) {
      const float mm = wave_min(dd[0]);
      if (dd[0] == mm) {
#pragma unroll
        for (int k = 0; k < KK - 1; ++k) dd[k] = dd[k + 1];
        dd[KK - 1] = BIG;
      }
      tau2 = mm;
    }
    acc = 0.f;
    for (int s0 = 0; s0 < steps; ++s0) {
      const int pos = lo2 + s0 * 64 + lane;
      if (pos < hi2) {
        const float4 c = sv[pos];
        const float dx = xi - c.x, dy = yi - c.y, dz = zi - c.z;
        const float d2 = fmaf(dx, dx, fmaf(dy, dy, dz * dz));
        const float w  = fmaf(W0, fabsf(dx), fmaf(W1, fabsf(dy), W2 * fabsf(dz)));
        acc += (d2 <= tau2) ? w : 0.f;
      }
    }
  }

  // ---- 6. reduce + write ----
#pragma unroll
  for (int o = 1; o < 64; o <<= 1) acc += __shfl_xor(acc, o);
  if (lane == 0) {
    const float xw0 = W0 * xi + W1 * yi + W2 * zi;
    // 1 + 11/sqrt(2)
    out[orig] = bb + (xw0 * 8.778174593052022f + 0.5f * acc) * (1.0f / 12.0f);
  }
}

extern "C" void kernel_launch(void* const* d_in, const int* in_sizes, int n_in,
                              void* d_out, int out_size, void* d_ws, size_t ws_size,
                              hipStream_t stream) {
  const float* p  = (const float*)d_in[0];
  const float* W  = (const float*)d_in[1];
  const float* bb = (const float*)d_in[2];
  float* out = (float*)d_out;

  const int n = in_sizes[0] / 3;   // 16384

  // ws layout:
  //   c_all @ 0     : 3*2048 ints  (bin ENDS, query prefix sums)
  //   s_all @ 24KB  : 3*n float4   (sorted arrays)
  int*    c_all = (int*)d_ws;
  float4* s_all = (float4*)((char*)d_ws + 3 * NBINS * 4);
  int*    cx = c_all;
  int*    cy = cx + NBINS;
  int*    cz = cy + NBINS;
  float4* sx = s_all;
  float4* sy = sx + n;
  float4* sz = sy + n;

  sort_kernel<<<3 * PARTS, 1024, 0, stream>>>(p, c_all, s_all, n);
  query_kernel<<<n / WPB, BLOCK, 0, stream>>>(sx, sy, sz, cx, cy, cz, W, bb, out, n);
}